// Round 6
// baseline (60.005 us; speedup 1.0000x reference)
//
#include <hip/hip_runtime.h>
#include <hip/hip_bf16.h>

typedef __attribute__((ext_vector_type(8))) short short8;
typedef __attribute__((ext_vector_type(4))) float f32x4;

#define LOG2E 1.4426950408889634f
#define PI_F 3.14159265358979323846f
#define NTOT 65536
#define BTOT 2048
#define DIM 64
#define NSPL 256         /* n-splits of 256 cols each */
#define NSTEP 16         /* 256 cols / 16 per step */
#define NTILES 512       /* NTOT / 128 (prep) */

/* ws layout (bytes) */
#define OFF_SVSBF 0u
#define OFF_XBF   8388608u
#define OFF_EB2   8650752u
#define OFF_A2    8912896u
#define OFF_PART  8921088u
#define WS_NEEDED 11018240u   /* OFF_PART + 256*2048*4 */

__device__ __forceinline__ unsigned short f2bf(float f) {
    union { __hip_bfloat16 h; unsigned short u; } c;
    c.h = __float2bfloat16(f);
    return c.u;
}

// ---------------- prepass: f32 -> bf16 (+norm factors) ----------------
__global__ __launch_bounds__(256) void kde_prep(
    const float* __restrict__ X, const float* __restrict__ svs,
    const float* __restrict__ scale_p, unsigned short* __restrict__ svs_bf,
    unsigned short* __restrict__ x_bf, float* __restrict__ eb2,
    float* __restrict__ a2nat) {
    const float scale = scale_p[0];
    const int tid = threadIdx.x;
    const int blk = blockIdx.x;
    if (blk < NTILES) {
#pragma unroll
        for (int i = 0; i < 4; ++i) {
            int g = i * 256 + tid;
            int row = g >> 3, grp = g & 7;
            const float* src = svs + ((size_t)blk * 128 + row) * DIM + grp * 8;
            float4 v0 = *(const float4*)src;
            float4 v1 = *(const float4*)(src + 4);
            float ss = v0.x * v0.x + v0.y * v0.y + v0.z * v0.z + v0.w * v0.w +
                       v1.x * v1.x + v1.y * v1.y + v1.z * v1.z + v1.w * v1.w;
            short8 o;
            o[0] = f2bf(v0.x); o[1] = f2bf(v0.y); o[2] = f2bf(v0.z); o[3] = f2bf(v0.w);
            o[4] = f2bf(v1.x); o[5] = f2bf(v1.y); o[6] = f2bf(v1.z); o[7] = f2bf(v1.w);
            *(short8*)(svs_bf + (size_t)blk * 8192 + row * 64 + grp * 8) = o;
            ss += __shfl_xor(ss, 1, 64);
            ss += __shfl_xor(ss, 2, 64);
            ss += __shfl_xor(ss, 4, 64);
            if (grp == 0)
                eb2[blk * 128 + row] = __builtin_amdgcn_exp2f(-scale * LOG2E * ss);
        }
    } else {
        const int t16 = blk - NTILES;
        const float C1 = 2.0f * scale * LOG2E;
#pragma unroll
        for (int i = 0; i < 4; ++i) {
            int g = i * 256 + tid;
            int row = g >> 3, grp = g & 7;
            const float* src = X + ((size_t)t16 * 128 + row) * DIM + grp * 8;
            float4 v0 = *(const float4*)src;
            float4 v1 = *(const float4*)(src + 4);
            float ss = v0.x * v0.x + v0.y * v0.y + v0.z * v0.z + v0.w * v0.w +
                       v1.x * v1.x + v1.y * v1.y + v1.z * v1.z + v1.w * v1.w;
            short8 o;
            o[0] = f2bf(v0.x * C1); o[1] = f2bf(v0.y * C1);
            o[2] = f2bf(v0.z * C1); o[3] = f2bf(v0.w * C1);
            o[4] = f2bf(v1.x * C1); o[5] = f2bf(v1.y * C1);
            o[6] = f2bf(v1.z * C1); o[7] = f2bf(v1.w * C1);
            *(short8*)(x_bf + ((size_t)t16 * 128 + row) * 64 + grp * 8) = o;
            ss += __shfl_xor(ss, 1, 64);
            ss += __shfl_xor(ss, 2, 64);
            ss += __shfl_xor(ss, 4, 64);
            if (grp == 0) a2nat[t16 * 128 + row] = -scale * ss;
        }
    }
}

// ---------------- main: barrier-free, register-direct MFMA ----------------
// 2048 blocks x 4 waves = 8192 waves (full machine). Each wave owns
// 64 M-rows x 256 N-cols; B fragments direct from L2 (XCD-clustered), 2-deep
// register pipeline (named A/B buffers, static indexing), no LDS, no barriers.
__global__ __launch_bounds__(256) void kde_main6(
    const unsigned short* __restrict__ svs_bf,
    const unsigned short* __restrict__ x_bf, const float* __restrict__ eb2,
    float* __restrict__ partials) {
    const int tid = threadIdx.x, lane = tid & 63, wave = tid >> 6;
    const int bid = blockIdx.x;             // 0..2047
    const int xcd = bid & 7, j = bid >> 3;  // j 0..255
    const int nsplit = ((j & 31) << 3) | xcd;  // 0..255, clustered per XCD
    const int mgroup = j >> 5;                 // 0..7
    const int mstrip = mgroup * 4 + wave;      // 0..31
    const int rowbase = mstrip * 64;
    const int col = lane & 15, krow = lane >> 4;

    // A fragments: 4 mf x (K=64 as 2 kf)
    short8 afrag[4][2];
#pragma unroll
    for (int mf = 0; mf < 4; ++mf) {
        const unsigned short* ap =
            x_bf + (size_t)(rowbase + mf * 16 + col) * 64 + krow * 8;
#pragma unroll
        for (int kf = 0; kf < 2; ++kf)
            afrag[mf][kf] = *(const short8*)(ap + kf * 32);
    }

    const unsigned short* bbase = svs_bf + (size_t)nsplit * 256 * 64;
    const float* ebase = eb2 + nsplit * 256;

    const f32x4 zacc = {0.f, 0.f, 0.f, 0.f};
    float s[4][4];
#pragma unroll
    for (int mf = 0; mf < 4; ++mf)
#pragma unroll
        for (int q = 0; q < 4; ++q) s[mf][q] = 0.f;

#define BPTR(t_) (bbase + (size_t)((t_)*16 + col) * 64 + krow * 8)
    // prologue: steps 0 (A-buf) and 1 (B-buf)
    short8 pa0 = *(const short8*)BPTR(0);
    short8 pa1 = *(const short8*)(BPTR(0) + 32);
    float pae = ebase[0 * 16 + col];
    short8 pb0 = *(const short8*)BPTR(1);
    short8 pb1 = *(const short8*)(BPTR(1) + 32);
    float pbe = ebase[1 * 16 + col];

#define COMPUTE(cb0_, cb1_, ce_)                                                   \
    do {                                                                           \
        _Pragma("unroll") for (int mf = 0; mf < 4; ++mf) {                         \
            f32x4 acc = __builtin_amdgcn_mfma_f32_16x16x32_bf16(afrag[mf][0],      \
                                                                (cb0_), zacc, 0, 0, 0); \
            acc = __builtin_amdgcn_mfma_f32_16x16x32_bf16(afrag[mf][1], (cb1_),    \
                                                          acc, 0, 0, 0);           \
            s[mf][0] = __builtin_fmaf(__builtin_amdgcn_exp2f(acc[0]), (ce_), s[mf][0]); \
            s[mf][1] = __builtin_fmaf(__builtin_amdgcn_exp2f(acc[1]), (ce_), s[mf][1]); \
            s[mf][2] = __builtin_fmaf(__builtin_amdgcn_exp2f(acc[2]), (ce_), s[mf][2]); \
            s[mf][3] = __builtin_fmaf(__builtin_amdgcn_exp2f(acc[3]), (ce_), s[mf][3]); \
        }                                                                          \
    } while (0)

#pragma unroll
    for (int i = 0; i < NSTEP / 2; ++i) {
        const int t = 2 * i;
        COMPUTE(pa0, pa1, pae);
        if (t + 2 < NSTEP) {  // static after unroll
            pa0 = *(const short8*)BPTR(t + 2);
            pa1 = *(const short8*)(BPTR(t + 2) + 32);
            pae = ebase[(t + 2) * 16 + col];
        }
        COMPUTE(pb0, pb1, pbe);
        if (t + 3 < NSTEP) {
            pb0 = *(const short8*)BPTR(t + 3);
            pb1 = *(const short8*)(BPTR(t + 3) + 32);
            pbe = ebase[(t + 3) * 16 + col];
        }
    }
#undef COMPUTE
#undef BPTR

    // sum the 16 col-lanes holding the same output rows
#pragma unroll
    for (int mask = 1; mask < 16; mask <<= 1)
#pragma unroll
        for (int mf = 0; mf < 4; ++mf)
#pragma unroll
            for (int q = 0; q < 4; ++q)
                s[mf][q] += __shfl_xor(s[mf][q], mask, 64);

    if (col == 0) {
#pragma unroll
        for (int mf = 0; mf < 4; ++mf)
#pragma unroll
            for (int q = 0; q < 4; ++q) {
                int row = rowbase + mf * 16 + krow * 4 + q;
                partials[(size_t)nsplit * BTOT + row] = s[mf][q];
            }
    }
}

__global__ void kde_final6(const float* __restrict__ partials,
                           const float* __restrict__ a2nat,
                           const float* __restrict__ scale_p,
                           float* __restrict__ out) {
    int b = blockIdx.x * 256 + threadIdx.x;
    if (b >= BTOT) return;
    float total = 0.f;
    for (int sidx = 0; sidx < NSPL; ++sidx)
        total += partials[(size_t)sidx * BTOT + b];
    out[b] = logf(total) + a2nat[b] - logf((float)NTOT) +
             32.0f * logf(scale_p[0] / PI_F);
}

// ================= fallback path (round-1, proven) =================
__device__ __forceinline__ int swz(int row, int kbyte) {
    return row * 128 + (kbyte ^ ((row & 7) << 4));
}

__global__ void fb_rownorm(const float* __restrict__ in,
                           const float* __restrict__ scale_p,
                           float* __restrict__ out, int nrows) {
    int t = blockIdx.x * 256 + threadIdx.x;
    int row = t >> 4;
    if (row >= nrows) return;
    int c4 = t & 15;
    float4 v = *(const float4*)&in[(size_t)row * 64 + c4 * 4];
    float ss = v.x * v.x + v.y * v.y + v.z * v.z + v.w * v.w;
    ss += __shfl_xor(ss, 1, 64);
    ss += __shfl_xor(ss, 2, 64);
    ss += __shfl_xor(ss, 4, 64);
    ss += __shfl_xor(ss, 8, 64);
    if (c4 == 0) out[row] = -scale_p[0] * LOG2E * ss;
}

__global__ __launch_bounds__(256) void fb_main(
    const float* __restrict__ X, const float* __restrict__ svs,
    const float* __restrict__ scale_p, const float* __restrict__ a2,
    const float* __restrict__ b2, float* __restrict__ partials) {
    __shared__ __align__(16) unsigned char ldsA[128 * 128];
    __shared__ __align__(16) unsigned char ldsBf[128 * 128];
    const int tid = threadIdx.x, lane = tid & 63, wave = tid >> 6;
    const int rowbase = blockIdx.x * 128, nbase = blockIdx.y * 512;
    const float C1 = 2.0f * scale_p[0] * LOG2E;
    {
        int r16 = tid >> 4, c4 = tid & 15;
        for (int p = 0; p < 8; ++p) {
            int row = p * 16 + r16;
            float4 v = *(const float4*)&X[(size_t)(rowbase + row) * 64 + c4 * 4];
            uint2 pk;
            pk.x = (unsigned)f2bf(v.x) | ((unsigned)f2bf(v.y) << 16);
            pk.y = (unsigned)f2bf(v.z) | ((unsigned)f2bf(v.w) << 16);
            *(uint2*)(ldsA + swz(row, c4 * 8)) = pk;
        }
    }
    __syncthreads();
    short8 afrag[2][2];
    {
        int arow = wave * 32 + (lane & 15);
        int kb = (lane >> 4) * 16;
        for (int mf = 0; mf < 2; ++mf)
            for (int kf = 0; kf < 2; ++kf)
                afrag[mf][kf] = *(const short8*)(ldsA + swz(arow + mf * 16, kb + kf * 64));
    }
    float a2l[2][4];
    for (int mf = 0; mf < 2; ++mf)
        for (int q = 0; q < 4; ++q)
            a2l[mf][q] = a2[rowbase + wave * 32 + mf * 16 + (lane >> 4) * 4 + q];
    float s[2][4] = {{0.f, 0.f, 0.f, 0.f}, {0.f, 0.f, 0.f, 0.f}};
    for (int itq = 0; itq < 4; ++itq) {
        int nb0 = nbase + itq * 128;
        __syncthreads();
        {
            int r16 = tid >> 4, c4 = tid & 15;
            for (int p = 0; p < 8; ++p) {
                int row = p * 16 + r16;
                float4 v = *(const float4*)&svs[(size_t)(nb0 + row) * 64 + c4 * 4];
                uint2 pk;
                pk.x = (unsigned)f2bf(v.x) | ((unsigned)f2bf(v.y) << 16);
                pk.y = (unsigned)f2bf(v.z) | ((unsigned)f2bf(v.w) << 16);
                *(uint2*)(ldsBf + swz(row, c4 * 8)) = pk;
            }
        }
        float b2l[8];
        for (int nf = 0; nf < 8; ++nf)
            b2l[nf] = b2[nb0 + nf * 16 + (lane & 15)];
        __syncthreads();
        for (int nf = 0; nf < 8; ++nf) {
            int brow = nf * 16 + (lane & 15);
            int kb = (lane >> 4) * 16;
            short8 b0 = *(const short8*)(ldsBf + swz(brow, kb));
            short8 b1 = *(const short8*)(ldsBf + swz(brow, kb + 64));
            for (int mf = 0; mf < 2; ++mf) {
                f32x4 acc = {0.f, 0.f, 0.f, 0.f};
                acc = __builtin_amdgcn_mfma_f32_16x16x32_bf16(afrag[mf][0], b0, acc, 0, 0, 0);
                acc = __builtin_amdgcn_mfma_f32_16x16x32_bf16(afrag[mf][1], b1, acc, 0, 0, 0);
                for (int q = 0; q < 4; ++q) {
                    float e = __builtin_fmaf(C1, acc[q], a2l[mf][q]) + b2l[nf];
                    s[mf][q] += __builtin_amdgcn_exp2f(e);
                }
            }
        }
    }
    for (int mask = 1; mask < 16; mask <<= 1)
        for (int mf = 0; mf < 2; ++mf)
            for (int q = 0; q < 4; ++q)
                s[mf][q] += __shfl_xor(s[mf][q], mask, 64);
    if ((lane & 15) == 0) {
        for (int mf = 0; mf < 2; ++mf)
            for (int q = 0; q < 4; ++q) {
                int row = rowbase + wave * 32 + mf * 16 + (lane >> 4) * 4 + q;
                partials[(size_t)blockIdx.y * BTOT + row] = s[mf][q];
            }
    }
}

__global__ void fb_final(const float* __restrict__ partials,
                         const float* __restrict__ scale_p,
                         float* __restrict__ out) {
    int b = blockIdx.x * 256 + threadIdx.x;
    if (b >= BTOT) return;
    float total = 0.f;
    for (int sidx = 0; sidx < 128; ++sidx)
        total += partials[(size_t)sidx * BTOT + b];
    out[b] = logf(total) - logf((float)NTOT) + 32.0f * logf(scale_p[0] / PI_F);
}

extern "C" void kernel_launch(void* const* d_in, const int* in_sizes, int n_in,
                              void* d_out, int out_size, void* d_ws,
                              size_t ws_size, hipStream_t stream) {
    const float* X = (const float*)d_in[0];
    const float* svs = (const float*)d_in[1];
    const float* scale_p = (const float*)d_in[2];
    unsigned char* ws = (unsigned char*)d_ws;

    if (ws_size >= WS_NEEDED) {
        unsigned short* svs_bf = (unsigned short*)(ws + OFF_SVSBF);
        unsigned short* x_bf = (unsigned short*)(ws + OFF_XBF);
        float* eb2 = (float*)(ws + OFF_EB2);
        float* a2nat = (float*)(ws + OFF_A2);
        float* partials = (float*)(ws + OFF_PART);
        kde_prep<<<NTILES + 16, 256, 0, stream>>>(X, svs, scale_p, svs_bf, x_bf,
                                                  eb2, a2nat);
        kde_main6<<<2048, 256, 0, stream>>>(svs_bf, x_bf, eb2, partials);
        kde_final6<<<BTOT / 256, 256, 0, stream>>>(partials, a2nat, scale_p,
                                                   (float*)d_out);
    } else {
        float* wsf = (float*)d_ws;
        float* b2 = wsf;
        float* a2 = wsf + NTOT;
        float* partials = wsf + NTOT + BTOT;
        fb_rownorm<<<(NTOT * 16) / 256, 256, 0, stream>>>(svs, scale_p, b2, NTOT);
        fb_rownorm<<<(BTOT * 16) / 256, 256, 0, stream>>>(X, scale_p, a2, BTOT);
        dim3 grid(BTOT / 128, 128);
        fb_main<<<grid, 256, 0, stream>>>(X, svs, scale_p, a2, b2, partials);
        fb_final<<<BTOT / 256, 256, 0, stream>>>(partials, scale_p, (float*)d_out);
    }
}

// Round 7
// 52.598 us; speedup vs baseline: 1.1408x; 1.1408x over previous
//
#include <hip/hip_runtime.h>
#include <hip/hip_bf16.h>

typedef __attribute__((ext_vector_type(8))) short short8;
typedef __attribute__((ext_vector_type(4))) float f32x4;

#define LOG2E 1.4426950408889634f
#define PI_F 3.14159265358979323846f
#define NTOT 65536
#define BTOT 2048
#define DIM 64
#define NSPL 256         /* n-splits of 256 cols each */
#define NTILES 512       /* NTOT / 128 (prep) */

/* ws layout (bytes) */
#define OFF_SVSBF 0u
#define OFF_XBF   8388608u
#define OFF_EB2   8650752u
#define OFF_A2    8912896u
#define OFF_PART  8921088u
#define WS_NEEDED 11018240u   /* OFF_PART + 256*2048*4 */

__device__ __forceinline__ unsigned short f2bf(float f) {
    union { __hip_bfloat16 h; unsigned short u; } c;
    c.h = __float2bfloat16(f);
    return c.u;
}

// ---------------- prepass: f32 -> bf16 (+norm factors) ----------------
__global__ __launch_bounds__(256) void kde_prep(
    const float* __restrict__ X, const float* __restrict__ svs,
    const float* __restrict__ scale_p, unsigned short* __restrict__ svs_bf,
    unsigned short* __restrict__ x_bf, float* __restrict__ eb2,
    float* __restrict__ a2nat) {
    const float scale = scale_p[0];
    const int tid = threadIdx.x;
    const int blk = blockIdx.x;
    if (blk < NTILES) {
#pragma unroll
        for (int i = 0; i < 4; ++i) {
            int g = i * 256 + tid;
            int row = g >> 3, grp = g & 7;
            const float* src = svs + ((size_t)blk * 128 + row) * DIM + grp * 8;
            float4 v0 = *(const float4*)src;
            float4 v1 = *(const float4*)(src + 4);
            float ss = v0.x * v0.x + v0.y * v0.y + v0.z * v0.z + v0.w * v0.w +
                       v1.x * v1.x + v1.y * v1.y + v1.z * v1.z + v1.w * v1.w;
            short8 o;
            o[0] = f2bf(v0.x); o[1] = f2bf(v0.y); o[2] = f2bf(v0.z); o[3] = f2bf(v0.w);
            o[4] = f2bf(v1.x); o[5] = f2bf(v1.y); o[6] = f2bf(v1.z); o[7] = f2bf(v1.w);
            *(short8*)(svs_bf + (size_t)blk * 8192 + row * 64 + grp * 8) = o;
            ss += __shfl_xor(ss, 1, 64);
            ss += __shfl_xor(ss, 2, 64);
            ss += __shfl_xor(ss, 4, 64);
            if (grp == 0)
                eb2[blk * 128 + row] = __builtin_amdgcn_exp2f(-scale * LOG2E * ss);
        }
    } else {
        const int t16 = blk - NTILES;
        const float C1 = 2.0f * scale * LOG2E;
#pragma unroll
        for (int i = 0; i < 4; ++i) {
            int g = i * 256 + tid;
            int row = g >> 3, grp = g & 7;
            const float* src = X + ((size_t)t16 * 128 + row) * DIM + grp * 8;
            float4 v0 = *(const float4*)src;
            float4 v1 = *(const float4*)(src + 4);
            float ss = v0.x * v0.x + v0.y * v0.y + v0.z * v0.z + v0.w * v0.w +
                       v1.x * v1.x + v1.y * v1.y + v1.z * v1.z + v1.w * v1.w;
            short8 o;
            o[0] = f2bf(v0.x * C1); o[1] = f2bf(v0.y * C1);
            o[2] = f2bf(v0.z * C1); o[3] = f2bf(v0.w * C1);
            o[4] = f2bf(v1.x * C1); o[5] = f2bf(v1.y * C1);
            o[6] = f2bf(v1.z * C1); o[7] = f2bf(v1.w * C1);
            *(short8*)(x_bf + ((size_t)t16 * 128 + row) * 64 + grp * 8) = o;
            ss += __shfl_xor(ss, 1, 64);
            ss += __shfl_xor(ss, 2, 64);
            ss += __shfl_xor(ss, 4, 64);
            if (grp == 0) a2nat[t16 * 128 + row] = -scale * ss;
        }
    }
}

// ---------------- main: barrier-free, DMA-ring MFMA ----------------
// Each wave owns 64 M-rows x 256 N-cols. B step-tiles DMA'd into a
// wave-PRIVATE 3-slot LDS ring via global_load_lds (counted vmcnt, never
// drained mid-loop); no __syncthreads anywhere. In-slot XOR swizzle is
// applied on the GLOBAL source address (linear LDS dest), read back with the
// matching XOR so ds_read_b128 is bank-balanced.
__global__ __launch_bounds__(256) void kde_main7(
    const unsigned short* __restrict__ svs_bf,
    const unsigned short* __restrict__ x_bf, const float* __restrict__ eb2,
    float* __restrict__ partials) {
    __shared__ __align__(16) unsigned char ring[4][3][2048];
    __shared__ __align__(16) float ebl[4][256];

    const int tid = threadIdx.x, lane = tid & 63, wave = tid >> 6;
    const int bid = blockIdx.x;             // 0..2047
    const int xcd = bid & 7, j = bid >> 3;  // j 0..255
    const int nsplit = ((j & 31) << 3) | xcd;  // 0..255, clustered per XCD
    const int mgroup = j >> 5;                 // 0..7
    const int rowbase = (mgroup * 4 + wave) * 64;
    const int col = lane & 15, krow = lane >> 4, c7 = col & 7;

    // A fragments: 4 mf x (K=64 as 2 kf), direct from global
    short8 afrag[4][2];
#pragma unroll
    for (int mf = 0; mf < 4; ++mf) {
        const unsigned short* ap =
            x_bf + (size_t)(rowbase + mf * 16 + col) * 64 + krow * 8;
#pragma unroll
        for (int kf = 0; kf < 2; ++kf)
            afrag[mf][kf] = *(const short8*)(ap + kf * 32);
    }

    // eb2 chunk -> per-wave LDS (1 KB), via 4 size-4 global_load_lds
    {
        const float* ebase = eb2 + nsplit * 256;
#pragma unroll
        for (int i = 0; i < 4; ++i)
            __builtin_amdgcn_global_load_lds(
                (const __attribute__((address_space(1))) void*)(ebase + i * 64 + lane),
                (__attribute__((address_space(3))) void*)&ebl[wave][i * 64], 4, 0, 0);
    }

    const unsigned char* gsv =
        (const unsigned char*)svs_bf + (size_t)nsplit * 32768;
    // source-side swizzle: linear LDS pos (col', q) receives k-seg q^(col'&7)
    const int lane_off =
        ((lane >> 3) << 7) | ((((lane & 7) ^ (lane >> 3))) << 4);

#define STAGE(t_)                                                                  \
    do {                                                                           \
        const unsigned char* gt_ = gsv + (t_) * 2048 + lane_off;                   \
        unsigned char* d_ = &ring[wave][(t_) % 3][0];                              \
        __builtin_amdgcn_global_load_lds(                                          \
            (const __attribute__((address_space(1))) void*)gt_,                    \
            (__attribute__((address_space(3))) void*)d_, 16, 0, 0);                \
        __builtin_amdgcn_global_load_lds(                                          \
            (const __attribute__((address_space(1))) void*)(gt_ + 1024),           \
            (__attribute__((address_space(3))) void*)(d_ + 1024), 16, 0, 0);       \
    } while (0)

#define READB(t_, r0_, r1_)                                                        \
    do {                                                                           \
        const unsigned char* sp_ = &ring[wave][(t_) % 3][0];                       \
        r0_ = *(const short8*)(sp_ + col * 128 + ((krow ^ c7) << 4));              \
        r1_ = *(const short8*)(sp_ + col * 128 + (((krow + 4) ^ c7) << 4));        \
    } while (0)

    // drain afrag + ebl loads so the vmcnt ledger below counts stages only
    asm volatile("s_waitcnt vmcnt(0)" ::: "memory");
    STAGE(0); STAGE(1); STAGE(2);   // 6 outstanding

    const f32x4 zacc = {0.f, 0.f, 0.f, 0.f};
    float s[4][4];
#pragma unroll
    for (int mf = 0; mf < 4; ++mf)
#pragma unroll
        for (int q = 0; q < 4; ++q) s[mf][q] = 0.f;

#define COMPUTE(cb0_, cb1_, ce_)                                                   \
    do {                                                                           \
        _Pragma("unroll") for (int mf = 0; mf < 4; ++mf) {                         \
            f32x4 acc = __builtin_amdgcn_mfma_f32_16x16x32_bf16(afrag[mf][0],      \
                                                                (cb0_), zacc, 0, 0, 0); \
            acc = __builtin_amdgcn_mfma_f32_16x16x32_bf16(afrag[mf][1], (cb1_),    \
                                                          acc, 0, 0, 0);           \
            s[mf][0] = __builtin_fmaf(__builtin_amdgcn_exp2f(acc[0]), (ce_), s[mf][0]); \
            s[mf][1] = __builtin_fmaf(__builtin_amdgcn_exp2f(acc[1]), (ce_), s[mf][1]); \
            s[mf][2] = __builtin_fmaf(__builtin_amdgcn_exp2f(acc[2]), (ce_), s[mf][2]); \
            s[mf][3] = __builtin_fmaf(__builtin_amdgcn_exp2f(acc[3]), (ce_), s[mf][3]); \
        }                                                                          \
    } while (0)

    short8 rb0, rb1, nb0 = {}, nb1 = {};
    asm volatile("s_waitcnt vmcnt(4)" ::: "memory");  // slot 0 landed
    READB(0, rb0, rb1);

#pragma unroll
    for (int t = 0; t < 16; ++t) {
        // ledger: outstanding stages {t+1, t+2} (4 instrs, or fewer at tail)
        if (t <= 13) {
            asm volatile("s_waitcnt vmcnt(2)" ::: "memory");  // t+1 landed
        } else if (t == 14) {
            asm volatile("s_waitcnt vmcnt(0)" ::: "memory");  // 15 landed
        }
        float ce = ebl[wave][t * 16 + col];
        if (t < 15) READB(t + 1, nb0, nb1);
        COMPUTE(rb0, rb1, ce);
        if (t + 3 < 16) STAGE(t + 3);  // overwrites slot t%3 (already consumed)
        rb0 = nb0; rb1 = nb1;
    }
#undef COMPUTE
#undef READB
#undef STAGE

    // sum the 16 col-lanes holding the same output rows
#pragma unroll
    for (int mask = 1; mask < 16; mask <<= 1)
#pragma unroll
        for (int mf = 0; mf < 4; ++mf)
#pragma unroll
            for (int q = 0; q < 4; ++q)
                s[mf][q] += __shfl_xor(s[mf][q], mask, 64);

    if (col == 0) {
#pragma unroll
        for (int mf = 0; mf < 4; ++mf)
#pragma unroll
            for (int q = 0; q < 4; ++q) {
                int row = rowbase + mf * 16 + krow * 4 + q;
                partials[(size_t)nsplit * BTOT + row] = s[mf][q];
            }
    }
}

__global__ void kde_final7(const float* __restrict__ partials,
                           const float* __restrict__ a2nat,
                           const float* __restrict__ scale_p,
                           float* __restrict__ out) {
    int b = blockIdx.x * 256 + threadIdx.x;
    if (b >= BTOT) return;
    float total = 0.f;
    for (int sidx = 0; sidx < NSPL; ++sidx)
        total += partials[(size_t)sidx * BTOT + b];
    out[b] = logf(total) + a2nat[b] - logf((float)NTOT) +
             32.0f * logf(scale_p[0] / PI_F);
}

// ================= fallback path (round-1, proven) =================
__device__ __forceinline__ int swz(int row, int kbyte) {
    return row * 128 + (kbyte ^ ((row & 7) << 4));
}

__global__ void fb_rownorm(const float* __restrict__ in,
                           const float* __restrict__ scale_p,
                           float* __restrict__ out, int nrows) {
    int t = blockIdx.x * 256 + threadIdx.x;
    int row = t >> 4;
    if (row >= nrows) return;
    int c4 = t & 15;
    float4 v = *(const float4*)&in[(size_t)row * 64 + c4 * 4];
    float ss = v.x * v.x + v.y * v.y + v.z * v.z + v.w * v.w;
    ss += __shfl_xor(ss, 1, 64);
    ss += __shfl_xor(ss, 2, 64);
    ss += __shfl_xor(ss, 4, 64);
    ss += __shfl_xor(ss, 8, 64);
    if (c4 == 0) out[row] = -scale_p[0] * LOG2E * ss;
}

__global__ __launch_bounds__(256) void fb_main(
    const float* __restrict__ X, const float* __restrict__ svs,
    const float* __restrict__ scale_p, const float* __restrict__ a2,
    const float* __restrict__ b2, float* __restrict__ partials) {
    __shared__ __align__(16) unsigned char ldsA[128 * 128];
    __shared__ __align__(16) unsigned char ldsBf[128 * 128];
    const int tid = threadIdx.x, lane = tid & 63, wave = tid >> 6;
    const int rowbase = blockIdx.x * 128, nbase = blockIdx.y * 512;
    const float C1 = 2.0f * scale_p[0] * LOG2E;
    {
        int r16 = tid >> 4, c4 = tid & 15;
        for (int p = 0; p < 8; ++p) {
            int row = p * 16 + r16;
            float4 v = *(const float4*)&X[(size_t)(rowbase + row) * 64 + c4 * 4];
            uint2 pk;
            pk.x = (unsigned)f2bf(v.x) | ((unsigned)f2bf(v.y) << 16);
            pk.y = (unsigned)f2bf(v.z) | ((unsigned)f2bf(v.w) << 16);
            *(uint2*)(ldsA + swz(row, c4 * 8)) = pk;
        }
    }
    __syncthreads();
    short8 afrag[2][2];
    {
        int arow = wave * 32 + (lane & 15);
        int kb = (lane >> 4) * 16;
        for (int mf = 0; mf < 2; ++mf)
            for (int kf = 0; kf < 2; ++kf)
                afrag[mf][kf] = *(const short8*)(ldsA + swz(arow + mf * 16, kb + kf * 64));
    }
    float a2l[2][4];
    for (int mf = 0; mf < 2; ++mf)
        for (int q = 0; q < 4; ++q)
            a2l[mf][q] = a2[rowbase + wave * 32 + mf * 16 + (lane >> 4) * 4 + q];
    float s[2][4] = {{0.f, 0.f, 0.f, 0.f}, {0.f, 0.f, 0.f, 0.f}};
    for (int itq = 0; itq < 4; ++itq) {
        int nb0 = nbase + itq * 128;
        __syncthreads();
        {
            int r16 = tid >> 4, c4 = tid & 15;
            for (int p = 0; p < 8; ++p) {
                int row = p * 16 + r16;
                float4 v = *(const float4*)&svs[(size_t)(nb0 + row) * 64 + c4 * 4];
                uint2 pk;
                pk.x = (unsigned)f2bf(v.x) | ((unsigned)f2bf(v.y) << 16);
                pk.y = (unsigned)f2bf(v.z) | ((unsigned)f2bf(v.w) << 16);
                *(uint2*)(ldsBf + swz(row, c4 * 8)) = pk;
            }
        }
        float b2l[8];
        for (int nf = 0; nf < 8; ++nf)
            b2l[nf] = b2[nb0 + nf * 16 + (lane & 15)];
        __syncthreads();
        for (int nf = 0; nf < 8; ++nf) {
            int brow = nf * 16 + (lane & 15);
            int kb = (lane >> 4) * 16;
            short8 b0 = *(const short8*)(ldsBf + swz(brow, kb));
            short8 b1 = *(const short8*)(ldsBf + swz(brow, kb + 64));
            for (int mf = 0; mf < 2; ++mf) {
                f32x4 acc = {0.f, 0.f, 0.f, 0.f};
                acc = __builtin_amdgcn_mfma_f32_16x16x32_bf16(afrag[mf][0], b0, acc, 0, 0, 0);
                acc = __builtin_amdgcn_mfma_f32_16x16x32_bf16(afrag[mf][1], b1, acc, 0, 0, 0);
                for (int q = 0; q < 4; ++q) {
                    float e = __builtin_fmaf(C1, acc[q], a2l[mf][q]) + b2l[nf];
                    s[mf][q] += __builtin_amdgcn_exp2f(e);
                }
            }
        }
    }
    for (int mask = 1; mask < 16; mask <<= 1)
        for (int mf = 0; mf < 2; ++mf)
            for (int q = 0; q < 4; ++q)
                s[mf][q] += __shfl_xor(s[mf][q], mask, 64);
    if ((lane & 15) == 0) {
        for (int mf = 0; mf < 2; ++mf)
            for (int q = 0; q < 4; ++q) {
                int row = rowbase + wave * 32 + mf * 16 + (lane >> 4) * 4 + q;
                partials[(size_t)blockIdx.y * BTOT + row] = s[mf][q];
            }
    }
}

__global__ void fb_final(const float* __restrict__ partials,
                         const float* __restrict__ scale_p,
                         float* __restrict__ out) {
    int b = blockIdx.x * 256 + threadIdx.x;
    if (b >= BTOT) return;
    float total = 0.f;
    for (int sidx = 0; sidx < 128; ++sidx)
        total += partials[(size_t)sidx * BTOT + b];
    out[b] = logf(total) - logf((float)NTOT) + 32.0f * logf(scale_p[0] / PI_F);
}

extern "C" void kernel_launch(void* const* d_in, const int* in_sizes, int n_in,
                              void* d_out, int out_size, void* d_ws,
                              size_t ws_size, hipStream_t stream) {
    const float* X = (const float*)d_in[0];
    const float* svs = (const float*)d_in[1];
    const float* scale_p = (const float*)d_in[2];
    unsigned char* ws = (unsigned char*)d_ws;

    if (ws_size >= WS_NEEDED) {
        unsigned short* svs_bf = (unsigned short*)(ws + OFF_SVSBF);
        unsigned short* x_bf = (unsigned short*)(ws + OFF_XBF);
        float* eb2 = (float*)(ws + OFF_EB2);
        float* a2nat = (float*)(ws + OFF_A2);
        float* partials = (float*)(ws + OFF_PART);
        kde_prep<<<NTILES + 16, 256, 0, stream>>>(X, svs, scale_p, svs_bf, x_bf,
                                                  eb2, a2nat);
        kde_main7<<<2048, 256, 0, stream>>>(svs_bf, x_bf, eb2, partials);
        kde_final7<<<BTOT / 256, 256, 0, stream>>>(partials, a2nat, scale_p,
                                                   (float*)d_out);
    } else {
        float* wsf = (float*)d_ws;
        float* b2 = wsf;
        float* a2 = wsf + NTOT;
        float* partials = wsf + NTOT + BTOT;
        fb_rownorm<<<(NTOT * 16) / 256, 256, 0, stream>>>(svs, scale_p, b2, NTOT);
        fb_rownorm<<<(BTOT * 16) / 256, 256, 0, stream>>>(X, scale_p, a2, BTOT);
        dim3 grid(BTOT / 128, 128);
        fb_main<<<grid, 256, 0, stream>>>(X, svs, scale_p, a2, b2, partials);
        fb_final<<<BTOT / 256, 256, 0, stream>>>(partials, scale_p, (float*)d_out);
    }
}